// Round 1
// baseline (924.234 us; speedup 1.0000x reference)
//
#include <hip/hip_runtime.h>
#include <stdint.h>

// Problem constants
#define DM 1024
#define NHEAD 8
#define DK 128
#define BATCH 4
#define SEQ 8192
#define ROWS (BATCH*SEQ)       // 32768
#define EPSL 1e-5f
#define NSPLIT 8

typedef __attribute__((ext_vector_type(8)))  short    bf16x8;
typedef __attribute__((ext_vector_type(4)))  short    short4v;
typedef __attribute__((ext_vector_type(4)))  float    f32x4;
typedef __attribute__((ext_vector_type(4)))  float    float4v;
typedef __attribute__((ext_vector_type(2)))  uint32_t uint2v;
typedef __attribute__((ext_vector_type(4)))  uint32_t uint4v;

union AFrag { bf16x8 v; short4v h[2]; int i4[4]; };
union U8    { uint4v v[2]; uint32_t u[8]; };

// round-half-up fp32 -> bf16, packed pair (a in low16, b in high16)
__device__ inline uint32_t pack2bf(float a, float b){
  uint32_t ua = __builtin_bit_cast(uint32_t, a) + 0x8000u;
  uint32_t ub = __builtin_bit_cast(uint32_t, b) + 0x8000u;
  return (ua >> 16) | (ub & 0xffff0000u);
}

// ---------------- weight fp32 -> bf16 convert (Wk, Wv) ----------------
__global__ void wconv_kernel(const float* __restrict__ src, uint32_t* __restrict__ dst, int n8){
  int i = blockIdx.x*256 + threadIdx.x;
  if (i >= n8) return;
  const float4v* s = (const float4v*)src;
  float4v v0 = s[2*i], v1 = s[2*i+1];
  uint4v o;
  o.x = pack2bf(v0.x, v0.y); o.y = pack2bf(v0.z, v0.w);
  o.z = pack2bf(v1.x, v1.y); o.w = pack2bf(v1.z, v1.w);
  ((uint4v*)dst)[i] = o;
}

// ---------------- main GEMM core ----------------
// MODE 0: C = LN_perhead(A@Bw^T + bias) -> bf16 outb   (K/V projection + layernorm)
// MODE 1: C = A@Bw_b^T + bias_b         -> f32  outf   (final att GEMM, per-batch B)
template<int MODE>
__global__ __launch_bounds__(256, 2)
void gemm_core(const float* __restrict__ A, const uint16_t* __restrict__ Bw,
               const float* __restrict__ bias, const float* __restrict__ gamma,
               const float* __restrict__ beta, uint16_t* __restrict__ outb,
               float* __restrict__ outf)
{
  __shared__ uint16_t As[128][36];   // pitch 36: 18-dword row stride (<=2-way banks), 8B aligned rows
  __shared__ uint16_t Bs[128][36];
  __shared__ float red_s[2][128];
  __shared__ float red_q[2][128];

  const int tid = threadIdx.x;
  const int bN = blockIdx.x, bM = blockIdx.y;
  const int lane = tid & 63, wv = tid >> 6;
  const int wm = wv & 1, wn = wv >> 1;
  const int l15 = lane & 15, l4 = lane >> 4;

  // staging: thread -> (row, half of 32-wide k-slab)
  const int sr = tid >> 1, sh = tid & 1;
  const float* Ap = A + (size_t)(bM*128 + sr)*DM + sh*16;
  const uint16_t* Bbase = Bw + (MODE==1 ? (size_t)(bM>>6)*1048576 : (size_t)0);
  const uint16_t* Bp = Bbase + (size_t)(bN*128 + sr)*DM + sh*16;
  uint32_t* asw = (uint32_t*)&As[sr][sh*16];
  uint32_t* bsw = (uint32_t*)&Bs[sr][sh*16];

  f32x4 acc[4][4];
  #pragma unroll
  for (int i=0;i<4;i++)
    #pragma unroll
    for (int j=0;j<4;j++) acc[i][j] = (f32x4)(0.0f);

  const uint16_t* Ard = &As[wm*64 + l15][l4*8];
  const uint16_t* Brd = &Bs[wn*64 + l15][l4*8];

  for (int k0 = 0; k0 < DM; k0 += 32){
    float4v a0 = *(const float4v*)(Ap);
    float4v a1 = *(const float4v*)(Ap+4);
    float4v a2 = *(const float4v*)(Ap+8);
    float4v a3 = *(const float4v*)(Ap+12);
    uint4v b0 = *(const uint4v*)(Bp);
    uint4v b1 = *(const uint4v*)(Bp+8);
    Ap += 32; Bp += 32;
    uint32_t p0 = pack2bf(a0.x,a0.y), p1 = pack2bf(a0.z,a0.w);
    uint32_t p2 = pack2bf(a1.x,a1.y), p3 = pack2bf(a1.z,a1.w);
    uint32_t p4 = pack2bf(a2.x,a2.y), p5 = pack2bf(a2.z,a2.w);
    uint32_t p6 = pack2bf(a3.x,a3.y), p7 = pack2bf(a3.z,a3.w);
    __syncthreads();  // previous compute done before overwrite
    { uint2v t; t.x=p0;   t.y=p1;   ((uint2v*)asw)[0]=t; }
    { uint2v t; t.x=p2;   t.y=p3;   ((uint2v*)asw)[1]=t; }
    { uint2v t; t.x=p4;   t.y=p5;   ((uint2v*)asw)[2]=t; }
    { uint2v t; t.x=p6;   t.y=p7;   ((uint2v*)asw)[3]=t; }
    { uint2v t; t.x=b0.x; t.y=b0.y; ((uint2v*)bsw)[0]=t; }
    { uint2v t; t.x=b0.z; t.y=b0.w; ((uint2v*)bsw)[1]=t; }
    { uint2v t; t.x=b1.x; t.y=b1.y; ((uint2v*)bsw)[2]=t; }
    { uint2v t; t.x=b1.z; t.y=b1.w; ((uint2v*)bsw)[3]=t; }
    __syncthreads();

    AFrag af[4], bf4[4];
    #pragma unroll
    for (int mt=0; mt<4; mt++){
      af[mt].h[0] = *(const short4v*)(Ard + mt*16*36);
      af[mt].h[1] = *(const short4v*)(Ard + mt*16*36 + 4);
    }
    #pragma unroll
    for (int nt=0; nt<4; nt++){
      bf4[nt].h[0] = *(const short4v*)(Brd + nt*16*36);
      bf4[nt].h[1] = *(const short4v*)(Brd + nt*16*36 + 4);
    }
    #pragma unroll
    for (int mt=0; mt<4; mt++)
      #pragma unroll
      for (int nt=0; nt<4; nt++)
        acc[mt][nt] = __builtin_amdgcn_mfma_f32_16x16x32_bf16(af[mt].v, bf4[nt].v, acc[mt][nt], 0, 0, 0);
  }

  if (MODE == 0){
    // epilogue: bias add, per-row (128-col, one head) layernorm, gamma/beta, bf16 store
    float bv[4], gv[4], btv[4];
    #pragma unroll
    for (int nt=0; nt<4; nt++){
      int col = bN*128 + wn*64 + nt*16 + l15;
      bv[nt] = bias[col]; gv[nt] = gamma[col]; btv[nt] = beta[col];
    }
    #pragma unroll
    for (int mt=0; mt<4; mt++){
      #pragma unroll
      for (int i=0; i<4; i++){
        float sm = 0.f, sq = 0.f;
        #pragma unroll
        for (int nt=0; nt<4; nt++){
          float v = acc[mt][nt][i] + bv[nt];
          acc[mt][nt][i] = v;
          sm += v; sq += v*v;
        }
        #pragma unroll
        for (int off=1; off<16; off<<=1){
          sm += __shfl_xor(sm, off, 16);
          sq += __shfl_xor(sq, off, 16);
        }
        if (l15 == 0){
          int rl = wm*64 + mt*16 + l4*4 + i;
          red_s[wn][rl] = sm; red_q[wn][rl] = sq;
        }
      }
    }
    __syncthreads();
    #pragma unroll
    for (int mt=0; mt<4; mt++){
      #pragma unroll
      for (int i=0; i<4; i++){
        int rl = wm*64 + mt*16 + l4*4 + i;
        float sum = red_s[0][rl] + red_s[1][rl];
        float ssq = red_q[0][rl] + red_q[1][rl];
        float mean = sum * (1.f/DK);
        float var  = ssq * (1.f/DK) - mean*mean;
        float rs   = rsqrtf(var + EPSL);
        size_t row = (size_t)(bM*128 + rl);
        #pragma unroll
        for (int nt=0; nt<4; nt++){
          int col = bN*128 + wn*64 + nt*16 + l15;
          float o = (acc[mt][nt][i] - mean)*rs*gv[nt] + btv[nt];
          uint32_t u = __builtin_bit_cast(uint32_t, o) + 0x8000u;
          outb[row*DM + col] = (uint16_t)(u >> 16);
        }
      }
    }
  } else {
    const int bb = bM >> 6;  // 64 M-blocks per batch
    float bv[4];
    #pragma unroll
    for (int nt=0; nt<4; nt++)
      bv[nt] = bias[bb*DM + bN*128 + wn*64 + nt*16 + l15];
    #pragma unroll
    for (int mt=0; mt<4; mt++){
      #pragma unroll
      for (int i=0; i<4; i++){
        size_t row = (size_t)(bM*128 + wm*64 + mt*16 + l4*4 + i);
        #pragma unroll
        for (int nt=0; nt<4; nt++){
          int col = bN*128 + wn*64 + nt*16 + l15;
          outf[row*DM + col] = acc[mt][nt][i] + bv[nt];
        }
      }
    }
  }
}

// ---------------- scores: per (b,h,split) partial K^T V ----------------
__global__ __launch_bounds__(256, 2)
void scores_kernel(const uint16_t* __restrict__ kln, const uint16_t* __restrict__ vln,
                   float* __restrict__ part)
{
  __shared__ uint16_t kT[128][70];  // [d][n], pitch 70 (35-dword stride: <=2-way banks on frag reads)
  __shared__ uint16_t vT[128][70];  // [e][n]
  const int tid = threadIdx.x;
  const int sp = blockIdx.x & 7, bh = blockIdx.x >> 3;
  const int b = bh >> 3, h = bh & 7;
  const int lane = tid & 63, wv = tid >> 6, wm = wv & 1, wn = wv >> 1;
  const int l15 = lane & 15, l4 = lane >> 4;
  const int dg = tid & 7, np = tid >> 3;   // dg: 16-wide d group, np: n-pair 0..31

  f32x4 acc[4][4];
  #pragma unroll
  for (int i=0;i<4;i++)
    #pragma unroll
    for (int j=0;j<4;j++) acc[i][j] = (f32x4)(0.0f);

  const size_t hb = (size_t)b*SEQ*DM + (size_t)h*DK;
  for (int nc = 0; nc < 16; nc++){
    const int n0 = sp*1024 + nc*64;
    const uint16_t* kp = kln + hb + (size_t)(n0 + 2*np)*DM + dg*16;
    const uint16_t* vp = vln + hb + (size_t)(n0 + 2*np)*DM + dg*16;
    U8 k0, k1, v0, v1;
    k0.v[0] = *(const uint4v*)(kp);       k0.v[1] = *(const uint4v*)(kp+8);
    k1.v[0] = *(const uint4v*)(kp+DM);    k1.v[1] = *(const uint4v*)(kp+DM+8);
    v0.v[0] = *(const uint4v*)(vp);       v0.v[1] = *(const uint4v*)(vp+8);
    v1.v[0] = *(const uint4v*)(vp+DM);    v1.v[1] = *(const uint4v*)(vp+DM+8);
    __syncthreads();
    #pragma unroll
    for (int q=0; q<8; q++){
      uint32_t ke = (k0.u[q] & 0xffffu) | (k1.u[q] << 16);
      uint32_t ko = (k0.u[q] >> 16)     | (k1.u[q] & 0xffff0000u);
      uint32_t ve = (v0.u[q] & 0xffffu) | (v1.u[q] << 16);
      uint32_t vo = (v0.u[q] >> 16)     | (v1.u[q] & 0xffff0000u);
      int d = dg*16 + q*2;
      *(uint32_t*)&kT[d  ][2*np] = ke;
      *(uint32_t*)&kT[d+1][2*np] = ko;
      *(uint32_t*)&vT[d  ][2*np] = ve;
      *(uint32_t*)&vT[d+1][2*np] = vo;
    }
    __syncthreads();
    #pragma unroll
    for (int ks=0; ks<2; ks++){
      const int koff = ks*32 + l4*8;
      AFrag af[4], bf4[4];
      #pragma unroll
      for (int mt=0; mt<4; mt++){
        const uint16_t* pr = &kT[wm*64 + mt*16 + l15][koff];
        af[mt].i4[0] = *(const int*)(pr);
        af[mt].i4[1] = *(const int*)(pr+2);
        af[mt].i4[2] = *(const int*)(pr+4);
        af[mt].i4[3] = *(const int*)(pr+6);
      }
      #pragma unroll
      for (int nt=0; nt<4; nt++){
        const uint16_t* pr = &vT[wn*64 + nt*16 + l15][koff];
        bf4[nt].i4[0] = *(const int*)(pr);
        bf4[nt].i4[1] = *(const int*)(pr+2);
        bf4[nt].i4[2] = *(const int*)(pr+4);
        bf4[nt].i4[3] = *(const int*)(pr+6);
      }
      #pragma unroll
      for (int mt=0; mt<4; mt++)
        #pragma unroll
        for (int nt=0; nt<4; nt++)
          acc[mt][nt] = __builtin_amdgcn_mfma_f32_16x16x32_bf16(af[mt].v, bf4[nt].v, acc[mt][nt], 0, 0, 0);
    }
  }
  float* po = part + (size_t)(sp*32 + bh)*16384;
  #pragma unroll
  for (int mt=0; mt<4; mt++)
    #pragma unroll
    for (int i=0; i<4; i++){
      int d = wm*64 + mt*16 + l4*4 + i;
      #pragma unroll
      for (int nt=0; nt<4; nt++){
        int e = wn*64 + nt*16 + l15;
        po[d*128 + e] = acc[mt][nt][i];
      }
    }
}

// ---------------- reduce split partials -> p_attn (scaled 1/N) ----------------
__global__ void reduce_kernel(const float* __restrict__ part, float* __restrict__ pout){
  int i = blockIdx.x*256 + threadIdx.x;   // 131072 float4 units over 524288 floats
  const float4v* p4 = (const float4v*)part;
  float4v s = p4[i];
  #pragma unroll
  for (int sp2=1; sp2<NSPLIT; sp2++) s += p4[(size_t)sp2*131072 + i];
  s *= (1.0f/(float)SEQ);
  ((float4v*)pout)[i] = s;
}

// ---------------- fold: WcT[b][col=h*128+e][D] = sum_f Wq[h*128+f][D] * p[b,h,f,e] ----------------
__global__ __launch_bounds__(256)
void fold_kernel(const float* __restrict__ Wq, const float* __restrict__ p,
                 uint16_t* __restrict__ WcT)
{
  const int dblk = blockIdx.x, h = blockIdx.y, b = blockIdx.z;
  const int t = threadIdx.x;
  const int eg = t & 15, dq = t >> 4;
  const int e0 = eg*8, d0 = dq*8;
  const float* pbase = p + (size_t)((b*NHEAD + h)*DK)*DK;           // p[f][e]
  const float* wbase = Wq + (size_t)h*DK*DM + dblk*128;             // Wq[h*128+f][dblk*128 + d]
  float accf[8][8];
  #pragma unroll
  for (int i=0;i<8;i++)
    #pragma unroll
    for (int j=0;j<8;j++) accf[i][j] = 0.f;
  for (int f=0; f<DK; f++){
    float4v pa = *(const float4v*)(pbase + f*DK + e0);
    float4v pc = *(const float4v*)(pbase + f*DK + e0 + 4);
    float4v wa = *(const float4v*)(wbase + (size_t)f*DM + d0);
    float4v wc = *(const float4v*)(wbase + (size_t)f*DM + d0 + 4);
    float pe[8] = {pa.x,pa.y,pa.z,pa.w,pc.x,pc.y,pc.z,pc.w};
    float we[8] = {wa.x,wa.y,wa.z,wa.w,wc.x,wc.y,wc.z,wc.w};
    #pragma unroll
    for (int i=0;i<8;i++)
      #pragma unroll
      for (int j=0;j<8;j++) accf[i][j] += pe[i]*we[j];
  }
  uint16_t* ob = WcT + (size_t)b*1048576 + (size_t)(h*DK)*DM + dblk*128;
  #pragma unroll
  for (int i=0;i<8;i++){
    uint4v ov;
    ov.x = pack2bf(accf[i][0], accf[i][1]);
    ov.y = pack2bf(accf[i][2], accf[i][3]);
    ov.z = pack2bf(accf[i][4], accf[i][5]);
    ov.w = pack2bf(accf[i][6], accf[i][7]);
    *(uint4v*)(ob + (size_t)(e0+i)*DM + d0) = ov;
  }
}

// ---------------- bc[b][col] = sum_f bq[h*128+f] * p[b,h,f,e] ----------------
__global__ void bc_kernel(const float* __restrict__ bq, const float* __restrict__ p,
                          float* __restrict__ bc)
{
  int gid = blockIdx.x*256 + threadIdx.x;  // 4096
  int b = gid >> 10, col = gid & 1023, h = col >> 7, e = col & 127;
  float s = 0.f;
  for (int f=0; f<DK; f++)
    s += bq[h*DK + f] * p[(size_t)((b*NHEAD + h)*DK + f)*DK + e];
  bc[gid] = s;
}

extern "C" void kernel_launch(void* const* d_in, const int* in_sizes, int n_in,
                              void* d_out, int out_size, void* d_ws, size_t ws_size,
                              hipStream_t stream)
{
  const float* query = (const float*)d_in[0];
  const float* key   = (const float*)d_in[1];
  const float* value = (const float*)d_in[2];
  const float* Wq    = (const float*)d_in[3];
  const float* bq    = (const float*)d_in[4];
  const float* Wk    = (const float*)d_in[5];
  const float* bk    = (const float*)d_in[6];
  const float* Wv    = (const float*)d_in[7];
  const float* bv    = (const float*)d_in[8];
  const float* gK    = (const float*)d_in[9];
  const float* bK    = (const float*)d_in[10];
  const float* gV    = (const float*)d_in[11];
  const float* bV    = (const float*)d_in[12];
  float* out = (float*)d_out;

  char* ws = (char*)d_ws;
  uint16_t* kln  = (uint16_t*)(ws);                    // 67108864 B
  uint16_t* vln  = (uint16_t*)(ws + 67108864);         // 67108864 B
  uint16_t* wkb  = (uint16_t*)(ws + 134217728);        // 2097152 B
  uint16_t* wvb  = (uint16_t*)(ws + 136314880);        // 2097152 B
  float*    part = (float*)   (ws + 138412032);        // 16777216 B
  uint16_t* wct  = (uint16_t*)(ws + 155189248);        // 8388608 B
  float*    bc   = (float*)   (ws + 163577856);        // 16384 B  (total 163594240)

  float* pout = out + 33554432;   // p_attn output region [4,8,128,128]

  wconv_kernel<<<512, 256, 0, stream>>>(Wk, (uint32_t*)wkb, 131072);
  wconv_kernel<<<512, 256, 0, stream>>>(Wv, (uint32_t*)wvb, 131072);
  gemm_core<0><<<dim3(8,256), 256, 0, stream>>>(key,   wkb, bk, gK, bK, kln, nullptr);
  gemm_core<0><<<dim3(8,256), 256, 0, stream>>>(value, wvb, bv, gV, bV, vln, nullptr);
  scores_kernel<<<256, 256, 0, stream>>>(kln, vln, part);
  reduce_kernel<<<512, 256, 0, stream>>>(part, pout);
  fold_kernel<<<dim3(8,8,4), 256, 0, stream>>>(Wq, pout, wct);
  bc_kernel<<<16, 256, 0, stream>>>(bq, pout, bc);
  gemm_core<1><<<dim3(8,256), 256, 0, stream>>>(query, wct, bc, nullptr, nullptr, nullptr, out);
}

// Round 2
// 879.005 us; speedup vs baseline: 1.0515x; 1.0515x over previous
//
#include <hip/hip_runtime.h>
#include <stdint.h>

// Problem constants
#define DM 1024
#define NHEAD 8
#define DK 128
#define BATCH 4
#define SEQ 8192
#define ROWS (BATCH*SEQ)       // 32768
#define EPSL 1e-5f
#define NSPLIT 8

typedef __attribute__((ext_vector_type(8)))  short    bf16x8;
typedef __attribute__((ext_vector_type(4)))  short    short4v;
typedef __attribute__((ext_vector_type(4)))  float    f32x4;
typedef __attribute__((ext_vector_type(4)))  float    float4v;
typedef __attribute__((ext_vector_type(2)))  uint32_t uint2v;
typedef __attribute__((ext_vector_type(4)))  uint32_t uint4v;

union AFrag { bf16x8 v; short4v h[2]; int i4[4]; };
union U8    { uint4v v[2]; uint32_t u[8]; };

// round-half-up fp32 -> bf16, packed pair (a in low16, b in high16)
__device__ inline uint32_t pack2bf(float a, float b){
  uint32_t ua = __builtin_bit_cast(uint32_t, a) + 0x8000u;
  uint32_t ub = __builtin_bit_cast(uint32_t, b) + 0x8000u;
  return (ua >> 16) | (ub & 0xffff0000u);
}

// ---------------- weight fp32 -> bf16 convert (Wk, Wv) ----------------
__global__ void wconv_kernel(const float* __restrict__ src, uint32_t* __restrict__ dst, int n8){
  int i = blockIdx.x*256 + threadIdx.x;
  if (i >= n8) return;
  const float4v* s = (const float4v*)src;
  float4v v0 = s[2*i], v1 = s[2*i+1];
  uint4v o;
  o.x = pack2bf(v0.x, v0.y); o.y = pack2bf(v0.z, v0.w);
  o.z = pack2bf(v1.x, v1.y); o.w = pack2bf(v1.z, v1.w);
  ((uint4v*)dst)[i] = o;
}

// ---------------- main GEMM core ----------------
// MODE 0: C = LN_perhead(A@Bw^T + bias) -> bf16 outb   (K/V projection + layernorm)
// MODE 1: C = A@Bw_b^T + bias_b         -> f32  outf   (final att GEMM, per-batch B)
// Grid: 1D 2048 blocks; XCD-swizzled so the 8 bN-blocks sharing one bM-tile
// land consecutively on the SAME XCD (assumes round-robin id%8 -> XCD).
template<int MODE>
__global__ __launch_bounds__(256, 2)
void gemm_core(const float* __restrict__ A, const uint16_t* __restrict__ Bw,
               const float* __restrict__ bias, const float* __restrict__ gamma,
               const float* __restrict__ beta, uint16_t* __restrict__ outb,
               float* __restrict__ outf)
{
  __shared__ uint16_t As[128][36];   // pitch 36: 18-dword row stride (<=2-way banks), 8B aligned rows
  __shared__ uint16_t Bs[128][36];
  __shared__ float red_s[2][128];
  __shared__ float red_q[2][128];

  const int tid = threadIdx.x;
  // XCD-aware swizzle: xcd = id&7 handles bM % 8 == xcd, all 8 bN consecutive.
  const int id  = blockIdx.x;
  const int xcd = id & 7, j = id >> 3;
  const int bM  = ((j >> 3) << 3) | xcd;   // 0..255
  const int bN  = j & 7;                   // 0..7
  const int lane = tid & 63, wv = tid >> 6;
  const int wm = wv & 1, wn = wv >> 1;
  const int l15 = lane & 15, l4 = lane >> 4;

  // staging: thread -> (row, half of 32-wide k-slab)
  const int sr = tid >> 1, sh = tid & 1;
  const float* Ap = A + (size_t)(bM*128 + sr)*DM + sh*16;
  const uint16_t* Bbase = Bw + (MODE==1 ? (size_t)(bM>>6)*1048576 : (size_t)0);
  const uint16_t* Bp = Bbase + (size_t)(bN*128 + sr)*DM + sh*16;
  uint32_t* asw = (uint32_t*)&As[sr][sh*16];
  uint32_t* bsw = (uint32_t*)&Bs[sr][sh*16];

  f32x4 acc[4][4];
  #pragma unroll
  for (int i=0;i<4;i++)
    #pragma unroll
    for (int jj=0;jj<4;jj++) acc[i][jj] = (f32x4)(0.0f);

  const uint16_t* Ard = &As[wm*64 + l15][l4*8];
  const uint16_t* Brd = &Bs[wn*64 + l15][l4*8];

  // software pipeline: prefetch slab 0
  float4v a0 = *(const float4v*)(Ap);
  float4v a1 = *(const float4v*)(Ap+4);
  float4v a2 = *(const float4v*)(Ap+8);
  float4v a3 = *(const float4v*)(Ap+12);
  uint4v  b0 = *(const uint4v*)(Bp);
  uint4v  b1 = *(const uint4v*)(Bp+8);
  Ap += 32; Bp += 32;

  for (int k0 = 0; k0 < DM; k0 += 32){
    uint32_t p0 = pack2bf(a0.x,a0.y), p1 = pack2bf(a0.z,a0.w);
    uint32_t p2 = pack2bf(a1.x,a1.y), p3 = pack2bf(a1.z,a1.w);
    uint32_t p4 = pack2bf(a2.x,a2.y), p5 = pack2bf(a2.z,a2.w);
    uint32_t p6 = pack2bf(a3.x,a3.y), p7 = pack2bf(a3.z,a3.w);
    uint4v  c0 = b0, c1 = b1;
    __syncthreads();  // previous compute reads done before overwrite
    { uint2v t; t.x=p0;   t.y=p1;   ((uint2v*)asw)[0]=t; }
    { uint2v t; t.x=p2;   t.y=p3;   ((uint2v*)asw)[1]=t; }
    { uint2v t; t.x=p4;   t.y=p5;   ((uint2v*)asw)[2]=t; }
    { uint2v t; t.x=p6;   t.y=p7;   ((uint2v*)asw)[3]=t; }
    { uint2v t; t.x=c0.x; t.y=c0.y; ((uint2v*)bsw)[0]=t; }
    { uint2v t; t.x=c0.z; t.y=c0.w; ((uint2v*)bsw)[1]=t; }
    { uint2v t; t.x=c1.x; t.y=c1.y; ((uint2v*)bsw)[2]=t; }
    { uint2v t; t.x=c1.z; t.y=c1.w; ((uint2v*)bsw)[3]=t; }
    __syncthreads();

    // prefetch next slab (overlaps with LDS reads + MFMA below)
    if (k0 + 32 < DM){
      a0 = *(const float4v*)(Ap);
      a1 = *(const float4v*)(Ap+4);
      a2 = *(const float4v*)(Ap+8);
      a3 = *(const float4v*)(Ap+12);
      b0 = *(const uint4v*)(Bp);
      b1 = *(const uint4v*)(Bp+8);
      Ap += 32; Bp += 32;
    }

    AFrag af[4], bf4[4];
    #pragma unroll
    for (int mt=0; mt<4; mt++){
      af[mt].h[0] = *(const short4v*)(Ard + mt*16*36);
      af[mt].h[1] = *(const short4v*)(Ard + mt*16*36 + 4);
    }
    #pragma unroll
    for (int nt=0; nt<4; nt++){
      bf4[nt].h[0] = *(const short4v*)(Brd + nt*16*36);
      bf4[nt].h[1] = *(const short4v*)(Brd + nt*16*36 + 4);
    }
    #pragma unroll
    for (int mt=0; mt<4; mt++)
      #pragma unroll
      for (int nt=0; nt<4; nt++)
        acc[mt][nt] = __builtin_amdgcn_mfma_f32_16x16x32_bf16(af[mt].v, bf4[nt].v, acc[mt][nt], 0, 0, 0);
  }

  if (MODE == 0){
    // epilogue: bias add, per-row (128-col, one head) layernorm, gamma/beta, bf16 store
    float bv[4], gv[4], btv[4];
    #pragma unroll
    for (int nt=0; nt<4; nt++){
      int col = bN*128 + wn*64 + nt*16 + l15;
      bv[nt] = bias[col]; gv[nt] = gamma[col]; btv[nt] = beta[col];
    }
    #pragma unroll
    for (int mt=0; mt<4; mt++){
      #pragma unroll
      for (int i=0; i<4; i++){
        float sm = 0.f, sq = 0.f;
        #pragma unroll
        for (int nt=0; nt<4; nt++){
          float v = acc[mt][nt][i] + bv[nt];
          acc[mt][nt][i] = v;
          sm += v; sq += v*v;
        }
        #pragma unroll
        for (int off=1; off<16; off<<=1){
          sm += __shfl_xor(sm, off, 16);
          sq += __shfl_xor(sq, off, 16);
        }
        if (l15 == 0){
          int rl = wm*64 + mt*16 + l4*4 + i;
          red_s[wn][rl] = sm; red_q[wn][rl] = sq;
        }
      }
    }
    __syncthreads();
    #pragma unroll
    for (int mt=0; mt<4; mt++){
      #pragma unroll
      for (int i=0; i<4; i++){
        int rl = wm*64 + mt*16 + l4*4 + i;
        float sum = red_s[0][rl] + red_s[1][rl];
        float ssq = red_q[0][rl] + red_q[1][rl];
        float mean = sum * (1.f/DK);
        float var  = ssq * (1.f/DK) - mean*mean;
        float rs   = rsqrtf(var + EPSL);
        size_t row = (size_t)(bM*128 + rl);
        #pragma unroll
        for (int nt=0; nt<4; nt++){
          int col = bN*128 + wn*64 + nt*16 + l15;
          float o = (acc[mt][nt][i] - mean)*rs*gv[nt] + btv[nt];
          uint32_t u = __builtin_bit_cast(uint32_t, o) + 0x8000u;
          outb[row*DM + col] = (uint16_t)(u >> 16);
        }
      }
    }
  } else {
    const int bb = bM >> 6;  // 64 M-blocks per batch
    float bv[4];
    #pragma unroll
    for (int nt=0; nt<4; nt++)
      bv[nt] = bias[bb*DM + bN*128 + wn*64 + nt*16 + l15];
    #pragma unroll
    for (int mt=0; mt<4; mt++){
      #pragma unroll
      for (int i=0; i<4; i++){
        size_t row = (size_t)(bM*128 + wm*64 + mt*16 + l4*4 + i);
        #pragma unroll
        for (int nt=0; nt<4; nt++){
          int col = bN*128 + wn*64 + nt*16 + l15;
          outf[row*DM + col] = acc[mt][nt][i] + bv[nt];
        }
      }
    }
  }
}

// ---------------- scores: per (b,h,split) partial K^T V ----------------
__global__ __launch_bounds__(256, 2)
void scores_kernel(const uint16_t* __restrict__ kln, const uint16_t* __restrict__ vln,
                   float* __restrict__ part)
{
  __shared__ uint16_t kT[128][70];  // [d][n], pitch 70 (35-dword stride: <=2-way banks on frag reads)
  __shared__ uint16_t vT[128][70];  // [e][n]
  const int tid = threadIdx.x;
  const int sp = blockIdx.x & 7, bh = blockIdx.x >> 3;
  const int b = bh >> 3, h = bh & 7;
  const int lane = tid & 63, wv = tid >> 6, wm = wv & 1, wn = wv >> 1;
  const int l15 = lane & 15, l4 = lane >> 4;
  const int dg = tid & 7, np = tid >> 3;   // dg: 16-wide d group, np: n-pair 0..31

  f32x4 acc[4][4];
  #pragma unroll
  for (int i=0;i<4;i++)
    #pragma unroll
    for (int jj=0;jj<4;jj++) acc[i][jj] = (f32x4)(0.0f);

  const size_t hb = (size_t)b*SEQ*DM + (size_t)h*DK;

  auto load_slab = [&](int nc, U8& k0, U8& k1, U8& v0, U8& v1){
    const int n0 = sp*1024 + nc*64;
    const uint16_t* kp = kln + hb + (size_t)(n0 + 2*np)*DM + dg*16;
    const uint16_t* vp = vln + hb + (size_t)(n0 + 2*np)*DM + dg*16;
    k0.v[0] = *(const uint4v*)(kp);       k0.v[1] = *(const uint4v*)(kp+8);
    k1.v[0] = *(const uint4v*)(kp+DM);    k1.v[1] = *(const uint4v*)(kp+DM+8);
    v0.v[0] = *(const uint4v*)(vp);       v0.v[1] = *(const uint4v*)(vp+8);
    v1.v[0] = *(const uint4v*)(vp+DM);    v1.v[1] = *(const uint4v*)(vp+DM+8);
  };

  U8 k0, k1, v0, v1;
  load_slab(0, k0, k1, v0, v1);

  for (int nc = 0; nc < 16; nc++){
    __syncthreads();  // previous compute reads done before overwrite
    #pragma unroll
    for (int q=0; q<8; q++){
      uint32_t ke = (k0.u[q] & 0xffffu) | (k1.u[q] << 16);
      uint32_t ko = (k0.u[q] >> 16)     | (k1.u[q] & 0xffff0000u);
      uint32_t ve = (v0.u[q] & 0xffffu) | (v1.u[q] << 16);
      uint32_t vo = (v0.u[q] >> 16)     | (v1.u[q] & 0xffff0000u);
      int d = dg*16 + q*2;
      *(uint32_t*)&kT[d  ][2*np] = ke;
      *(uint32_t*)&kT[d+1][2*np] = ko;
      *(uint32_t*)&vT[d  ][2*np] = ve;
      *(uint32_t*)&vT[d+1][2*np] = vo;
    }
    __syncthreads();

    if (nc + 1 < 16) load_slab(nc + 1, k0, k1, v0, v1);  // prefetch

    #pragma unroll
    for (int ks=0; ks<2; ks++){
      const int koff = ks*32 + l4*8;
      AFrag af[4], bf4[4];
      #pragma unroll
      for (int mt=0; mt<4; mt++){
        const uint16_t* pr = &kT[wm*64 + mt*16 + l15][koff];
        af[mt].i4[0] = *(const int*)(pr);
        af[mt].i4[1] = *(const int*)(pr+2);
        af[mt].i4[2] = *(const int*)(pr+4);
        af[mt].i4[3] = *(const int*)(pr+6);
      }
      #pragma unroll
      for (int nt=0; nt<4; nt++){
        const uint16_t* pr = &vT[wn*64 + nt*16 + l15][koff];
        bf4[nt].i4[0] = *(const int*)(pr);
        bf4[nt].i4[1] = *(const int*)(pr+2);
        bf4[nt].i4[2] = *(const int*)(pr+4);
        bf4[nt].i4[3] = *(const int*)(pr+6);
      }
      #pragma unroll
      for (int mt=0; mt<4; mt++)
        #pragma unroll
        for (int nt=0; nt<4; nt++)
          acc[mt][nt] = __builtin_amdgcn_mfma_f32_16x16x32_bf16(af[mt].v, bf4[nt].v, acc[mt][nt], 0, 0, 0);
    }
  }
  float* po = part + (size_t)(sp*32 + bh)*16384;
  #pragma unroll
  for (int mt=0; mt<4; mt++)
    #pragma unroll
    for (int i=0; i<4; i++){
      int d = wm*64 + mt*16 + l4*4 + i;
      #pragma unroll
      for (int nt=0; nt<4; nt++){
        int e = wn*64 + nt*16 + l15;
        po[d*128 + e] = acc[mt][nt][i];
      }
    }
}

// ---------------- reduce split partials -> p_attn (scaled 1/N) ----------------
__global__ void reduce_kernel(const float* __restrict__ part, float* __restrict__ pout){
  int i = blockIdx.x*256 + threadIdx.x;   // 131072 float4 units over 524288 floats
  const float4v* p4 = (const float4v*)part;
  float4v s = p4[i];
  #pragma unroll
  for (int sp2=1; sp2<NSPLIT; sp2++) s += p4[(size_t)sp2*131072 + i];
  s *= (1.0f/(float)SEQ);
  ((float4v*)pout)[i] = s;
}

// ---------------- fold: WcT[b][col=h*128+e][D] = sum_f Wq[h*128+f][D] * p[b,h,f,e] ----------------
__global__ __launch_bounds__(256)
void fold_kernel(const float* __restrict__ Wq, const float* __restrict__ p,
                 uint16_t* __restrict__ WcT)
{
  const int dblk = blockIdx.x, h = blockIdx.y, b = blockIdx.z;
  const int t = threadIdx.x;
  const int eg = t & 15, dq = t >> 4;
  const int e0 = eg*8, d0 = dq*8;
  const float* pbase = p + (size_t)((b*NHEAD + h)*DK)*DK;           // p[f][e]
  const float* wbase = Wq + (size_t)h*DK*DM + dblk*128;             // Wq[h*128+f][dblk*128 + d]
  float accf[8][8];
  #pragma unroll
  for (int i=0;i<8;i++)
    #pragma unroll
    for (int jj=0;jj<8;jj++) accf[i][jj] = 0.f;
  for (int f=0; f<DK; f++){
    float4v pa = *(const float4v*)(pbase + f*DK + e0);
    float4v pc = *(const float4v*)(pbase + f*DK + e0 + 4);
    float4v wa = *(const float4v*)(wbase + (size_t)f*DM + d0);
    float4v wc = *(const float4v*)(wbase + (size_t)f*DM + d0 + 4);
    float pe[8] = {pa.x,pa.y,pa.z,pa.w,pc.x,pc.y,pc.z,pc.w};
    float we[8] = {wa.x,wa.y,wa.z,wa.w,wc.x,wc.y,wc.z,wc.w};
    #pragma unroll
    for (int i=0;i<8;i++)
      #pragma unroll
      for (int jj=0;jj<8;jj++) accf[i][jj] += pe[i]*we[jj];
  }
  uint16_t* ob = WcT + (size_t)b*1048576 + (size_t)(h*DK)*DM + dblk*128;
  #pragma unroll
  for (int i=0;i<8;i++){
    uint4v ov;
    ov.x = pack2bf(accf[i][0], accf[i][1]);
    ov.y = pack2bf(accf[i][2], accf[i][3]);
    ov.z = pack2bf(accf[i][4], accf[i][5]);
    ov.w = pack2bf(accf[i][6], accf[i][7]);
    *(uint4v*)(ob + (size_t)(e0+i)*DM + d0) = ov;
  }
}

// ---------------- bc[b][col] = sum_f bq[h*128+f] * p[b,h,f,e] ----------------
__global__ void bc_kernel(const float* __restrict__ bq, const float* __restrict__ p,
                          float* __restrict__ bc)
{
  int gid = blockIdx.x*256 + threadIdx.x;  // 4096
  int b = gid >> 10, col = gid & 1023, h = col >> 7, e = col & 127;
  float s = 0.f;
  for (int f=0; f<DK; f++)
    s += bq[h*DK + f] * p[(size_t)((b*NHEAD + h)*DK + f)*DK + e];
  bc[gid] = s;
}

extern "C" void kernel_launch(void* const* d_in, const int* in_sizes, int n_in,
                              void* d_out, int out_size, void* d_ws, size_t ws_size,
                              hipStream_t stream)
{
  const float* query = (const float*)d_in[0];
  const float* key   = (const float*)d_in[1];
  const float* value = (const float*)d_in[2];
  const float* Wq    = (const float*)d_in[3];
  const float* bq    = (const float*)d_in[4];
  const float* Wk    = (const float*)d_in[5];
  const float* bk    = (const float*)d_in[6];
  const float* Wv    = (const float*)d_in[7];
  const float* bv    = (const float*)d_in[8];
  const float* gK    = (const float*)d_in[9];
  const float* bK    = (const float*)d_in[10];
  const float* gV    = (const float*)d_in[11];
  const float* bV    = (const float*)d_in[12];
  float* out = (float*)d_out;

  char* ws = (char*)d_ws;
  uint16_t* kln  = (uint16_t*)(ws);                    // 67108864 B
  uint16_t* vln  = (uint16_t*)(ws + 67108864);         // 67108864 B
  uint16_t* wkb  = (uint16_t*)(ws + 134217728);        // 2097152 B
  uint16_t* wvb  = (uint16_t*)(ws + 136314880);        // 2097152 B
  float*    part = (float*)   (ws + 138412032);        // 16777216 B
  uint16_t* wct  = (uint16_t*)(ws + 155189248);        // 8388608 B
  float*    bc   = (float*)   (ws + 163577856);        // 16384 B  (total 163594240)

  float* pout = out + 33554432;   // p_attn output region [4,8,128,128]

  wconv_kernel<<<512, 256, 0, stream>>>(Wk, (uint32_t*)wkb, 131072);
  wconv_kernel<<<512, 256, 0, stream>>>(Wv, (uint32_t*)wvb, 131072);
  gemm_core<0><<<2048, 256, 0, stream>>>(key,   wkb, bk, gK, bK, kln, nullptr);
  gemm_core<0><<<2048, 256, 0, stream>>>(value, wvb, bv, gV, bV, vln, nullptr);
  scores_kernel<<<256, 256, 0, stream>>>(kln, vln, part);
  reduce_kernel<<<512, 256, 0, stream>>>(part, pout);
  fold_kernel<<<dim3(8,8,4), 256, 0, stream>>>(Wq, pout, wct);
  bc_kernel<<<16, 256, 0, stream>>>(bq, pout, bc);
  gemm_core<1><<<2048, 256, 0, stream>>>(query, wct, bc, nullptr, nullptr, nullptr, out);
}

// Round 3
// 793.161 us; speedup vs baseline: 1.1653x; 1.1082x over previous
//
#include <hip/hip_runtime.h>
#include <stdint.h>

// Problem constants
#define DM 1024
#define NHEAD 8
#define DK 128
#define BATCH 4
#define SEQ 8192
#define ROWS (BATCH*SEQ)       // 32768
#define EPSL 1e-5f
#define NSPLIT 8

typedef __attribute__((ext_vector_type(8)))  short    bf16x8;
typedef __attribute__((ext_vector_type(4)))  short    short4v;
typedef __attribute__((ext_vector_type(4)))  float    f32x4;
typedef __attribute__((ext_vector_type(4)))  float    float4v;
typedef __attribute__((ext_vector_type(2)))  uint32_t uint2v;
typedef __attribute__((ext_vector_type(4)))  uint32_t uint4v;

union AFrag { bf16x8 v; short4v h[2]; int i4[4]; };
union U8    { uint4v v[2]; uint32_t u[8]; };

typedef __attribute__((address_space(1))) const unsigned int GU32;
typedef __attribute__((address_space(3))) unsigned int LU32;
__device__ __forceinline__ void gload16(const void* g, void* l){
  __builtin_amdgcn_global_load_lds((GU32*)g, (LU32*)l, 16, 0, 0);
}

// round-half-up fp32 -> bf16, packed pair (a in low16, b in high16)
__device__ inline uint32_t pack2bf(float a, float b){
  uint32_t ua = __builtin_bit_cast(uint32_t, a) + 0x8000u;
  uint32_t ub = __builtin_bit_cast(uint32_t, b) + 0x8000u;
  return (ua >> 16) | (ub & 0xffff0000u);
}

// ---------------- fp32 -> bf16 convert (weights and activations) ----------------
__global__ void conv_kernel(const float* __restrict__ src, uint32_t* __restrict__ dst, int n8){
  int i = blockIdx.x*256 + threadIdx.x;
  if (i >= n8) return;
  const float4v* s = (const float4v*)src;
  float4v v0 = s[2*i], v1 = s[2*i+1];
  uint4v o;
  o.x = pack2bf(v0.x, v0.y); o.y = pack2bf(v0.z, v0.w);
  o.z = pack2bf(v1.x, v1.y); o.w = pack2bf(v1.z, v1.w);
  ((uint4v*)dst)[i] = o;
}

// ---------------- m97-style bf16 GEMM ----------------
// MODE 0: C = LN_perhead(A@Bw^T + bias) -> bf16 outb   (K/V projection + layernorm)
// MODE 1: C = A@Bw_b^T + bias_b         -> f32  outf   (final att GEMM, per-batch B)
// A: bf16 [32768][1024]; Bw: bf16 [1024][1024] (B^T / weight layout), per-batch for MODE 1.
// BK=64, 128x128 tile. Staging via global_load_lds (16B/lane), chunk-rotation swizzle:
// LDS slot c of row r holds global k-chunk (c - r) & 7; read slot = (chunk + r) & 7.
// => fragment ds_read_b128 is 2-way bank aliased (free, m136).
template<int MODE>
__global__ __launch_bounds__(256, 2)
void gemm_bf(const uint16_t* __restrict__ A, const uint16_t* __restrict__ Bw,
             const float* __restrict__ bias, const float* __restrict__ gamma,
             const float* __restrict__ beta, uint16_t* __restrict__ outb,
             float* __restrict__ outf)
{
  __shared__ uint16_t As[128*64];
  __shared__ uint16_t Bs[128*64];
  __shared__ float red_s[2][128];
  __shared__ float red_q[2][128];

  const int tid = threadIdx.x;
  // XCD-aware swizzle: all 8 bN blocks of one bM land on the same XCD.
  const int id  = blockIdx.x;
  const int xcd = id & 7, jj0 = id >> 3;
  const int bM  = ((jj0 >> 3) << 3) | xcd;   // 0..255
  const int bN  = jj0 & 7;                   // 0..7
  const int lane = tid & 63, wv = tid >> 6;
  const int wm = wv & 1, wn = wv >> 1;
  const int l15 = lane & 15, l4 = lane >> 4;

  const int srow = tid >> 3;   // 0..31
  const int sc   = tid & 7;    // LDS slot 0..7

  const uint16_t* Ab = A + (size_t)(bM*128)*DM;
  const uint16_t* Bb = Bw + (MODE==1 ? (size_t)(bM>>6)*1048576 : (size_t)0)
                          + (size_t)(bN*128)*DM;

  f32x4 acc[4][4];
  #pragma unroll
  for (int i=0;i<4;i++)
    #pragma unroll
    for (int j=0;j<4;j++) acc[i][j] = (f32x4)(0.0f);

  for (int k0 = 0; k0 < DM; k0 += 64){
    __syncthreads();   // previous LDS reads done
    #pragma unroll
    for (int jr = 0; jr < 4; jr++){
      const int row = srow + 32*jr;
      const int g = (sc - row) & 7;           // global k-chunk fetched by this lane
      gload16(Ab + (size_t)row*DM + k0 + g*8, &As[row*64 + sc*8]);
      gload16(Bb + (size_t)row*DM + k0 + g*8, &Bs[row*64 + sc*8]);
    }
    __syncthreads();   // staged (compiler inserts vmcnt(0))

    #pragma unroll
    for (int ks = 0; ks < 2; ks++){
      AFrag af[4], bf4[4];
      #pragma unroll
      for (int mt=0; mt<4; mt++){
        const int r = wm*64 + mt*16 + l15;
        const int slot = (ks*4 + l4 + r) & 7;
        af[mt].v = *(const bf16x8*)&As[r*64 + slot*8];
      }
      #pragma unroll
      for (int nt=0; nt<4; nt++){
        const int r = wn*64 + nt*16 + l15;
        const int slot = (ks*4 + l4 + r) & 7;
        bf4[nt].v = *(const bf16x8*)&Bs[r*64 + slot*8];
      }
      #pragma unroll
      for (int mt=0; mt<4; mt++)
        #pragma unroll
        for (int nt=0; nt<4; nt++)
          acc[mt][nt] = __builtin_amdgcn_mfma_f32_16x16x32_bf16(af[mt].v, bf4[nt].v, acc[mt][nt], 0, 0, 0);
    }
  }

  if (MODE == 0){
    float bv[4], gv[4], btv[4];
    #pragma unroll
    for (int nt=0; nt<4; nt++){
      int col = bN*128 + wn*64 + nt*16 + l15;
      bv[nt] = bias[col]; gv[nt] = gamma[col]; btv[nt] = beta[col];
    }
    #pragma unroll
    for (int mt=0; mt<4; mt++){
      #pragma unroll
      for (int i=0; i<4; i++){
        float sm = 0.f, sq = 0.f;
        #pragma unroll
        for (int nt=0; nt<4; nt++){
          float v = acc[mt][nt][i] + bv[nt];
          acc[mt][nt][i] = v;
          sm += v; sq += v*v;
        }
        #pragma unroll
        for (int off=1; off<16; off<<=1){
          sm += __shfl_xor(sm, off, 16);
          sq += __shfl_xor(sq, off, 16);
        }
        if (l15 == 0){
          int rl = wm*64 + mt*16 + l4*4 + i;
          red_s[wn][rl] = sm; red_q[wn][rl] = sq;
        }
      }
    }
    __syncthreads();
    #pragma unroll
    for (int mt=0; mt<4; mt++){
      #pragma unroll
      for (int i=0; i<4; i++){
        int rl = wm*64 + mt*16 + l4*4 + i;
        float sum = red_s[0][rl] + red_s[1][rl];
        float ssq = red_q[0][rl] + red_q[1][rl];
        float mean = sum * (1.f/DK);
        float var  = ssq * (1.f/DK) - mean*mean;
        float rs   = rsqrtf(var + EPSL);
        size_t row = (size_t)(bM*128 + rl);
        #pragma unroll
        for (int nt=0; nt<4; nt++){
          int col = bN*128 + wn*64 + nt*16 + l15;
          float o = (acc[mt][nt][i] - mean)*rs*gv[nt] + btv[nt];
          uint32_t u = __builtin_bit_cast(uint32_t, o) + 0x8000u;
          outb[row*DM + col] = (uint16_t)(u >> 16);
        }
      }
    }
  } else {
    const int bb = bM >> 6;
    float bv[4];
    #pragma unroll
    for (int nt=0; nt<4; nt++)
      bv[nt] = bias[bb*DM + bN*128 + wn*64 + nt*16 + l15];
    #pragma unroll
    for (int mt=0; mt<4; mt++){
      #pragma unroll
      for (int i=0; i<4; i++){
        size_t row = (size_t)(bM*128 + wm*64 + mt*16 + l4*4 + i);
        #pragma unroll
        for (int nt=0; nt<4; nt++){
          int col = bN*128 + wn*64 + nt*16 + l15;
          outf[row*DM + col] = acc[mt][nt][i] + bv[nt];
        }
      }
    }
  }
}

// ---------------- fused fp32-A GEMM + LN (compact-ws fallback for V path) ----------------
__global__ __launch_bounds__(256, 2)
void gemm_fused(const float* __restrict__ A, const uint16_t* __restrict__ Bw,
                const float* __restrict__ bias, const float* __restrict__ gamma,
                const float* __restrict__ beta, uint16_t* __restrict__ outb)
{
  __shared__ uint16_t As[128][36];
  __shared__ uint16_t Bs[128][36];
  __shared__ float red_s[2][128];
  __shared__ float red_q[2][128];

  const int tid = threadIdx.x;
  const int id  = blockIdx.x;
  const int xcd = id & 7, j = id >> 3;
  const int bM  = ((j >> 3) << 3) | xcd;
  const int bN  = j & 7;
  const int lane = tid & 63, wv = tid >> 6;
  const int wm = wv & 1, wn = wv >> 1;
  const int l15 = lane & 15, l4 = lane >> 4;

  const int sr = tid >> 1, sh = tid & 1;
  const float* Ap = A + (size_t)(bM*128 + sr)*DM + sh*16;
  const uint16_t* Bp = Bw + (size_t)(bN*128 + sr)*DM + sh*16;
  uint32_t* asw = (uint32_t*)&As[sr][sh*16];
  uint32_t* bsw = (uint32_t*)&Bs[sr][sh*16];

  f32x4 acc[4][4];
  #pragma unroll
  for (int i=0;i<4;i++)
    #pragma unroll
    for (int jj=0;jj<4;jj++) acc[i][jj] = (f32x4)(0.0f);

  const uint16_t* Ard = &As[wm*64 + l15][l4*8];
  const uint16_t* Brd = &Bs[wn*64 + l15][l4*8];

  float4v a0 = *(const float4v*)(Ap);
  float4v a1 = *(const float4v*)(Ap+4);
  float4v a2 = *(const float4v*)(Ap+8);
  float4v a3 = *(const float4v*)(Ap+12);
  uint4v  b0 = *(const uint4v*)(Bp);
  uint4v  b1 = *(const uint4v*)(Bp+8);
  Ap += 32; Bp += 32;

  for (int k0 = 0; k0 < DM; k0 += 32){
    uint32_t p0 = pack2bf(a0.x,a0.y), p1 = pack2bf(a0.z,a0.w);
    uint32_t p2 = pack2bf(a1.x,a1.y), p3 = pack2bf(a1.z,a1.w);
    uint32_t p4 = pack2bf(a2.x,a2.y), p5 = pack2bf(a2.z,a2.w);
    uint32_t p6 = pack2bf(a3.x,a3.y), p7 = pack2bf(a3.z,a3.w);
    uint4v  c0 = b0, c1 = b1;
    __syncthreads();
    { uint2v t; t.x=p0;   t.y=p1;   ((uint2v*)asw)[0]=t; }
    { uint2v t; t.x=p2;   t.y=p3;   ((uint2v*)asw)[1]=t; }
    { uint2v t; t.x=p4;   t.y=p5;   ((uint2v*)asw)[2]=t; }
    { uint2v t; t.x=p6;   t.y=p7;   ((uint2v*)asw)[3]=t; }
    { uint2v t; t.x=c0.x; t.y=c0.y; ((uint2v*)bsw)[0]=t; }
    { uint2v t; t.x=c0.z; t.y=c0.w; ((uint2v*)bsw)[1]=t; }
    { uint2v t; t.x=c1.x; t.y=c1.y; ((uint2v*)bsw)[2]=t; }
    { uint2v t; t.x=c1.z; t.y=c1.w; ((uint2v*)bsw)[3]=t; }
    __syncthreads();

    if (k0 + 32 < DM){
      a0 = *(const float4v*)(Ap);
      a1 = *(const float4v*)(Ap+4);
      a2 = *(const float4v*)(Ap+8);
      a3 = *(const float4v*)(Ap+12);
      b0 = *(const uint4v*)(Bp);
      b1 = *(const uint4v*)(Bp+8);
      Ap += 32; Bp += 32;
    }

    AFrag af[4], bf4[4];
    #pragma unroll
    for (int mt=0; mt<4; mt++){
      af[mt].h[0] = *(const short4v*)(Ard + mt*16*36);
      af[mt].h[1] = *(const short4v*)(Ard + mt*16*36 + 4);
    }
    #pragma unroll
    for (int nt=0; nt<4; nt++){
      bf4[nt].h[0] = *(const short4v*)(Brd + nt*16*36);
      bf4[nt].h[1] = *(const short4v*)(Brd + nt*16*36 + 4);
    }
    #pragma unroll
    for (int mt=0; mt<4; mt++)
      #pragma unroll
      for (int nt=0; nt<4; nt++)
        acc[mt][nt] = __builtin_amdgcn_mfma_f32_16x16x32_bf16(af[mt].v, bf4[nt].v, acc[mt][nt], 0, 0, 0);
  }

  float bv[4], gv[4], btv[4];
  #pragma unroll
  for (int nt=0; nt<4; nt++){
    int col = bN*128 + wn*64 + nt*16 + l15;
    bv[nt] = bias[col]; gv[nt] = gamma[col]; btv[nt] = beta[col];
  }
  #pragma unroll
  for (int mt=0; mt<4; mt++){
    #pragma unroll
    for (int i=0; i<4; i++){
      float sm = 0.f, sq = 0.f;
      #pragma unroll
      for (int nt=0; nt<4; nt++){
        float v = acc[mt][nt][i] + bv[nt];
        acc[mt][nt][i] = v;
        sm += v; sq += v*v;
      }
      #pragma unroll
      for (int off=1; off<16; off<<=1){
        sm += __shfl_xor(sm, off, 16);
        sq += __shfl_xor(sq, off, 16);
      }
      if (l15 == 0){
        int rl = wm*64 + mt*16 + l4*4 + i;
        red_s[wn][rl] = sm; red_q[wn][rl] = sq;
      }
    }
  }
  __syncthreads();
  #pragma unroll
  for (int mt=0; mt<4; mt++){
    #pragma unroll
    for (int i=0; i<4; i++){
      int rl = wm*64 + mt*16 + l4*4 + i;
      float sum = red_s[0][rl] + red_s[1][rl];
      float ssq = red_q[0][rl] + red_q[1][rl];
      float mean = sum * (1.f/DK);
      float var  = ssq * (1.f/DK) - mean*mean;
      float rs   = rsqrtf(var + EPSL);
      size_t row = (size_t)(bM*128 + rl);
      #pragma unroll
      for (int nt=0; nt<4; nt++){
        int col = bN*128 + wn*64 + nt*16 + l15;
        float o = (acc[mt][nt][i] - mean)*rs*gv[nt] + btv[nt];
        uint32_t u = __builtin_bit_cast(uint32_t, o) + 0x8000u;
        outb[row*DM + col] = (uint16_t)(u >> 16);
      }
    }
  }
}

// ---------------- scores: per (b,h,split) partial K^T V ----------------
__global__ __launch_bounds__(256, 2)
void scores_kernel(const uint16_t* __restrict__ kln, const uint16_t* __restrict__ vln,
                   float* __restrict__ part)
{
  __shared__ uint16_t kT[128][70];
  __shared__ uint16_t vT[128][70];
  const int tid = threadIdx.x;
  const int sp = blockIdx.x & 7, bh = blockIdx.x >> 3;
  const int b = bh >> 3, h = bh & 7;
  const int lane = tid & 63, wv = tid >> 6, wm = wv & 1, wn = wv >> 1;
  const int l15 = lane & 15, l4 = lane >> 4;
  const int dg = tid & 7, np = tid >> 3;

  f32x4 acc[4][4];
  #pragma unroll
  for (int i=0;i<4;i++)
    #pragma unroll
    for (int jj=0;jj<4;jj++) acc[i][jj] = (f32x4)(0.0f);

  const size_t hb = (size_t)b*SEQ*DM + (size_t)h*DK;

  auto load_slab = [&](int nc, U8& k0, U8& k1, U8& v0, U8& v1){
    const int n0 = sp*1024 + nc*64;
    const uint16_t* kp = kln + hb + (size_t)(n0 + 2*np)*DM + dg*16;
    const uint16_t* vp = vln + hb + (size_t)(n0 + 2*np)*DM + dg*16;
    k0.v[0] = *(const uint4v*)(kp);       k0.v[1] = *(const uint4v*)(kp+8);
    k1.v[0] = *(const uint4v*)(kp+DM);    k1.v[1] = *(const uint4v*)(kp+DM+8);
    v0.v[0] = *(const uint4v*)(vp);       v0.v[1] = *(const uint4v*)(vp+8);
    v1.v[0] = *(const uint4v*)(vp+DM);    v1.v[1] = *(const uint4v*)(vp+DM+8);
  };

  U8 k0, k1, v0, v1;
  load_slab(0, k0, k1, v0, v1);

  for (int nc = 0; nc < 16; nc++){
    __syncthreads();
    #pragma unroll
    for (int q=0; q<8; q++){
      uint32_t ke = (k0.u[q] & 0xffffu) | (k1.u[q] << 16);
      uint32_t ko = (k0.u[q] >> 16)     | (k1.u[q] & 0xffff0000u);
      uint32_t ve = (v0.u[q] & 0xffffu) | (v1.u[q] << 16);
      uint32_t vo = (v0.u[q] >> 16)     | (v1.u[q] & 0xffff0000u);
      int d = dg*16 + q*2;
      *(uint32_t*)&kT[d  ][2*np] = ke;
      *(uint32_t*)&kT[d+1][2*np] = ko;
      *(uint32_t*)&vT[d  ][2*np] = ve;
      *(uint32_t*)&vT[d+1][2*np] = vo;
    }
    __syncthreads();

    if (nc + 1 < 16) load_slab(nc + 1, k0, k1, v0, v1);

    #pragma unroll
    for (int ks=0; ks<2; ks++){
      const int koff = ks*32 + l4*8;
      AFrag af[4], bf4[4];
      #pragma unroll
      for (int mt=0; mt<4; mt++){
        const uint16_t* pr = &kT[wm*64 + mt*16 + l15][koff];
        af[mt].i4[0] = *(const int*)(pr);
        af[mt].i4[1] = *(const int*)(pr+2);
        af[mt].i4[2] = *(const int*)(pr+4);
        af[mt].i4[3] = *(const int*)(pr+6);
      }
      #pragma unroll
      for (int nt=0; nt<4; nt++){
        const uint16_t* pr = &vT[wn*64 + nt*16 + l15][koff];
        bf4[nt].i4[0] = *(const int*)(pr);
        bf4[nt].i4[1] = *(const int*)(pr+2);
        bf4[nt].i4[2] = *(const int*)(pr+4);
        bf4[nt].i4[3] = *(const int*)(pr+6);
      }
      #pragma unroll
      for (int mt=0; mt<4; mt++)
        #pragma unroll
        for (int nt=0; nt<4; nt++)
          acc[mt][nt] = __builtin_amdgcn_mfma_f32_16x16x32_bf16(af[mt].v, bf4[nt].v, acc[mt][nt], 0, 0, 0);
    }
  }
  float* po = part + (size_t)(sp*32 + bh)*16384;
  #pragma unroll
  for (int mt=0; mt<4; mt++)
    #pragma unroll
    for (int i=0; i<4; i++){
      int d = wm*64 + mt*16 + l4*4 + i;
      #pragma unroll
      for (int nt=0; nt<4; nt++){
        int e = wn*64 + nt*16 + l15;
        po[d*128 + e] = acc[mt][nt][i];
      }
    }
}

// ---------------- reduce split partials -> p_attn (scaled 1/N) ----------------
__global__ void reduce_kernel(const float* __restrict__ part, float* __restrict__ pout){
  int i = blockIdx.x*256 + threadIdx.x;
  const float4v* p4 = (const float4v*)part;
  float4v s = p4[i];
  #pragma unroll
  for (int sp2=1; sp2<NSPLIT; sp2++) s += p4[(size_t)sp2*131072 + i];
  s *= (1.0f/(float)SEQ);
  ((float4v*)pout)[i] = s;
}

// ---------------- fold: WcT[b][col=h*128+e][D] = sum_f Wq[h*128+f][D] * p[b,h,f,e] ----------------
__global__ __launch_bounds__(256)
void fold_kernel(const float* __restrict__ Wq, const float* __restrict__ p,
                 uint16_t* __restrict__ WcT)
{
  const int dblk = blockIdx.x, h = blockIdx.y, b = blockIdx.z;
  const int t = threadIdx.x;
  const int eg = t & 15, dq = t >> 4;
  const int e0 = eg*8, d0 = dq*8;
  const float* pbase = p + (size_t)((b*NHEAD + h)*DK)*DK;
  const float* wbase = Wq + (size_t)h*DK*DM + dblk*128;
  float accf[8][8];
  #pragma unroll
  for (int i=0;i<8;i++)
    #pragma unroll
    for (int jj=0;jj<8;jj++) accf[i][jj] = 0.f;
  for (int f=0; f<DK; f++){
    float4v pa = *(const float4v*)(pbase + f*DK + e0);
    float4v pc = *(const float4v*)(pbase + f*DK + e0 + 4);
    float4v wa = *(const float4v*)(wbase + (size_t)f*DM + d0);
    float4v wc = *(const float4v*)(wbase + (size_t)f*DM + d0 + 4);
    float pe[8] = {pa.x,pa.y,pa.z,pa.w,pc.x,pc.y,pc.z,pc.w};
    float we[8] = {wa.x,wa.y,wa.z,wa.w,wc.x,wc.y,wc.z,wc.w};
    #pragma unroll
    for (int i=0;i<8;i++)
      #pragma unroll
      for (int jj=0;jj<8;jj++) accf[i][jj] += pe[i]*we[jj];
  }
  uint16_t* ob = WcT + (size_t)b*1048576 + (size_t)(h*DK)*DM + dblk*128;
  #pragma unroll
  for (int i=0;i<8;i++){
    uint4v ov;
    ov.x = pack2bf(accf[i][0], accf[i][1]);
    ov.y = pack2bf(accf[i][2], accf[i][3]);
    ov.z = pack2bf(accf[i][4], accf[i][5]);
    ov.w = pack2bf(accf[i][6], accf[i][7]);
    *(uint4v*)(ob + (size_t)(e0+i)*DM + d0) = ov;
  }
}

// ---------------- bc[b][col] = sum_f bq[h*128+f] * p[b,h,f,e] ----------------
__global__ void bc_kernel(const float* __restrict__ bq, const float* __restrict__ p,
                          float* __restrict__ bc)
{
  int gid = blockIdx.x*256 + threadIdx.x;
  int b = gid >> 10, col = gid & 1023, h = col >> 7, e = col & 127;
  float s = 0.f;
  for (int f=0; f<DK; f++)
    s += bq[h*DK + f] * p[(size_t)((b*NHEAD + h)*DK + f)*DK + e];
  bc[gid] = s;
}

extern "C" void kernel_launch(void* const* d_in, const int* in_sizes, int n_in,
                              void* d_out, int out_size, void* d_ws, size_t ws_size,
                              hipStream_t stream)
{
  const float* query = (const float*)d_in[0];
  const float* key   = (const float*)d_in[1];
  const float* value = (const float*)d_in[2];
  const float* Wq    = (const float*)d_in[3];
  const float* bq    = (const float*)d_in[4];
  const float* Wk    = (const float*)d_in[5];
  const float* bk    = (const float*)d_in[6];
  const float* Wv    = (const float*)d_in[7];
  const float* bv    = (const float*)d_in[8];
  const float* gK    = (const float*)d_in[9];
  const float* bK    = (const float*)d_in[10];
  const float* gV    = (const float*)d_in[11];
  const float* bV    = (const float*)d_in[12];
  float* out  = (float*)d_out;
  float* pout = out + 33554432;   // p_attn region [4,8,128,128]

  char* ws = (char*)d_ws;
  const int N8_ACT = 4194304;   // 32768*1024/8
  const int N8_W   = 131072;    // 1024*1024/8

  if (ws_size >= (size_t)364920832ull){
    // ---- big layout: all three GEMMs on the bf16 fast path ----
    uint16_t* kln = (uint16_t*)(ws);
    uint16_t* vln = (uint16_t*)(ws + 67108864);
    uint16_t* qbf = (uint16_t*)(ws + 134217728);
    uint16_t* kbf = (uint16_t*)(ws + 201326592);
    uint16_t* vbf = (uint16_t*)(ws + 268435456);
    uint16_t* wkb = (uint16_t*)(ws + 335544320);
    uint16_t* wvb = (uint16_t*)(ws + 337641472);
    float*    part= (float*)   (ws + 339738624);
    uint16_t* wct = (uint16_t*)(ws + 356515840);
    float*    bc  = (float*)   (ws + 364904448);

    conv_kernel<<<16384, 256, 0, stream>>>(key,   (uint32_t*)kbf, N8_ACT);
    conv_kernel<<<16384, 256, 0, stream>>>(value, (uint32_t*)vbf, N8_ACT);
    conv_kernel<<<16384, 256, 0, stream>>>(query, (uint32_t*)qbf, N8_ACT);
    conv_kernel<<<512,   256, 0, stream>>>(Wk,    (uint32_t*)wkb, N8_W);
    conv_kernel<<<512,   256, 0, stream>>>(Wv,    (uint32_t*)wvb, N8_W);
    gemm_bf<0><<<2048, 256, 0, stream>>>(kbf, wkb, bk, gK, bK, kln, nullptr);
    gemm_bf<0><<<2048, 256, 0, stream>>>(vbf, wvb, bv, gV, bV, vln, nullptr);
    scores_kernel<<<256, 256, 0, stream>>>(kln, vln, part);
    reduce_kernel<<<512, 256, 0, stream>>>(part, pout);
    fold_kernel<<<dim3(8,8,4), 256, 0, stream>>>(Wq, pout, wct);
    bc_kernel<<<16, 256, 0, stream>>>(bq, pout, bc);
    gemm_bf<1><<<2048, 256, 0, stream>>>(qbf, wct, bc, nullptr, nullptr, nullptr, out);
  } else {
    // ---- compact layout (<=136.3 MB ws) with buffer reuse; V path stays fused ----
    // region0 @0      (64MB): kbf -> (dead after gemmK) vln -> (dead after scores) wct/bc
    // region1 @64MB   (64MB): kln -> (dead after scores) qbf
    // wkb/wvb @128MB  (4MB); part lives in d_out att region (dead until final gemm)
    uint16_t* kbf = (uint16_t*)(ws);
    uint16_t* vln = (uint16_t*)(ws);                 // after kbf dead
    uint16_t* wct = (uint16_t*)(ws);                 // after vln dead
    float*    bc  = (float*)   (ws + 8388608);
    uint16_t* kln = (uint16_t*)(ws + 67108864);
    uint16_t* qbf = (uint16_t*)(ws + 67108864);      // after kln dead
    uint16_t* wkb = (uint16_t*)(ws + 134217728);
    uint16_t* wvb = (uint16_t*)(ws + 136314880);
    float*    part= (float*)   (d_out);              // 16MB, att region scratch

    conv_kernel<<<512,   256, 0, stream>>>(Wk,  (uint32_t*)wkb, N8_W);
    conv_kernel<<<512,   256, 0, stream>>>(Wv,  (uint32_t*)wvb, N8_W);
    conv_kernel<<<16384, 256, 0, stream>>>(key, (uint32_t*)kbf, N8_ACT);
    gemm_bf<0><<<2048, 256, 0, stream>>>(kbf, wkb, bk, gK, bK, kln, nullptr);
    gemm_fused<<<2048, 256, 0, stream>>>(value, wvb, bv, gV, bV, vln);
    scores_kernel<<<256, 256, 0, stream>>>(kln, vln, part);
    reduce_kernel<<<512, 256, 0, stream>>>(part, pout);
    conv_kernel<<<16384, 256, 0, stream>>>(query, (uint32_t*)qbf, N8_ACT);
    fold_kernel<<<dim3(8,8,4), 256, 0, stream>>>(Wq, pout, wct);
    bc_kernel<<<16, 256, 0, stream>>>(bq, pout, bc);
    gemm_bf<1><<<2048, 256, 0, stream>>>(qbf, wct, bc, nullptr, nullptr, nullptr, out);
  }
}